// Round 9
// baseline (92.408 us; speedup 1.0000x reference)
//
#include <hip/hip_runtime.h>
#include <math.h>

#define V_ 32000
#define E_ 1024
#define H_ 1024
#define S_ 2048

typedef __attribute__((ext_vector_type(8))) short bf16x8;
typedef __attribute__((ext_vector_type(8))) unsigned short u16x8;
typedef __attribute__((ext_vector_type(4))) float f32x4;

typedef __attribute__((address_space(1))) const unsigned int gu32;
typedef __attribute__((address_space(3))) unsigned int lu32;

__device__ __forceinline__ float sigmoidf_(float x) { return 1.0f / (1.0f + expf(-x)); }

__device__ __forceinline__ unsigned short f2bf(float f) {
    unsigned int u = __builtin_bit_cast(unsigned int, f);
    unsigned int r = (u + 0x7fffu + ((u >> 16) & 1u)) >> 16;
    return (unsigned short)r;
}
__device__ __forceinline__ float bf2f(unsigned short u) {
    return __builtin_bit_cast(float, ((unsigned int)u) << 16);
}
__device__ __forceinline__ u16x8 pack8(f32x4 a, f32x4 b) {
    u16x8 p;
    p[0] = f2bf(a[0]); p[1] = f2bf(a[1]); p[2] = f2bf(a[2]); p[3] = f2bf(a[3]);
    p[4] = f2bf(b[0]); p[5] = f2bf(b[1]); p[6] = f2bf(b[2]); p[7] = f2bf(b[3]);
    return p;
}
__device__ __forceinline__ void gload16(const void* g, void* l) {
    __builtin_amdgcn_global_load_lds((gu32*)g, (lu32*)l, 16, 0, 0);
}
__device__ __forceinline__ f32x4 ntload4(const float* p) {
    return __builtin_nontemporal_load((const f32x4*)p);
}

// ---------------- KA: LSTM (blocks 0..1023) || bf16 conversion (1024..1535) ----------------
__global__ __launch_bounds__(256) void kA(
    const float* __restrict__ W_ih, const float* __restrict__ W_hh,
    const float* __restrict__ b_ih, const float* __restrict__ b_hh,
    const float* __restrict__ last_context, const float* __restrict__ emb,
    const int* __restrict__ word, const float* __restrict__ h0,
    const float* __restrict__ c0, const float* __restrict__ enc,
    const float* __restrict__ W_attn,
    float* __restrict__ out_ht, float* __restrict__ out_c,
    float* __restrict__ ws_ht, unsigned short* __restrict__ encb,
    unsigned short* __restrict__ wab, float* __restrict__ ws_ctx)
{
    int b = blockIdx.x, tid = threadIdx.x;
    int wave = tid >> 6, lane = tid & 63;
    if (b < 1024) {
        __shared__ float sbuf[4];
        int j = b;
        const float* embrow = emb + (size_t)word[0] * E_;
        int row = j + wave * H_;
        const float* wi = W_ih + (size_t)row * (E_ + H_);
        const float* wh = W_hh + (size_t)row * H_;
        float acc = 0.f;
        #pragma unroll
        for (int it = 0; it < 8; ++it) {
            int idx = (lane + it * 64) * 4;
            f32x4 wv = ntload4(wi + idx);
            float4 xv = (idx < H_) ? *(const float4*)(last_context + idx)
                                   : *(const float4*)(embrow + (idx - H_));
            acc = fmaf(wv[0], xv.x, acc); acc = fmaf(wv[1], xv.y, acc);
            acc = fmaf(wv[2], xv.z, acc); acc = fmaf(wv[3], xv.w, acc);
        }
        #pragma unroll
        for (int it = 0; it < 4; ++it) {
            int idx = (lane + it * 64) * 4;
            f32x4 wv = ntload4(wh + idx);
            float4 hv = *(const float4*)(h0 + idx);
            acc = fmaf(wv[0], hv.x, acc); acc = fmaf(wv[1], hv.y, acc);
            acc = fmaf(wv[2], hv.z, acc); acc = fmaf(wv[3], hv.w, acc);
        }
        #pragma unroll
        for (int m = 32; m; m >>= 1) acc += __shfl_down(acc, m, 64);
        if (lane == 0) sbuf[wave] = acc;
        __syncthreads();
        if (tid == 0) {
            float gi = sbuf[0] + b_ih[j]          + b_hh[j];
            float gf = sbuf[1] + b_ih[j + H_]     + b_hh[j + H_];
            float gg = sbuf[2] + b_ih[j + 2*H_]   + b_hh[j + 2*H_];
            float go = sbuf[3] + b_ih[j + 3*H_]   + b_hh[j + 3*H_];
            float c  = sigmoidf_(gf) * c0[j] + sigmoidf_(gi) * tanhf(gg);
            float ht = sigmoidf_(go) * tanhf(c);
            out_c[j]  = c;
            out_ht[j] = ht;
            ws_ht[j]  = ht;
        }
        if (b == 0) {
            ws_ctx[tid]       = 0.f;
            ws_ctx[tid + 256] = 0.f;
            ws_ctx[tid + 512] = 0.f;
            ws_ctx[tid + 768] = 0.f;
        }
    } else {
        int cid = (b - 1024) * 256 + tid;
        const int ENC_CH = (S_ * E_) / 8;   // 262144
        #pragma unroll
        for (int i = 0; i < 3; ++i) {
            int idx = cid + i * 131072;
            const float* src;
            unsigned short* dst;
            if (idx < ENC_CH) {
                src = enc + (size_t)idx * 8;
                dst = encb + (size_t)idx * 8;
            } else {
                int w = idx - ENC_CH;
                int h = w >> 7, off = (w & 127) * 8;
                src = W_attn + (size_t)h * (E_ + H_) + H_ + off;
                dst = wab + (size_t)h * E_ + off;
            }
            f32x4 a = ntload4(src);
            f32x4 bq = ntload4(src + 4);
            *(u16x8*)dst = pack8(a, bq);
        }
    }
}

// ---------------- KC: scores GEMM with q-matvec hidden in the k-loop ----------------
// grid (32,16) = 512 blocks, 256 thr = 4 waves (2x2; wave tile 32x32).
// BM=64, BN=64, BK=64; single-buffered 16 KB LDS; q row (wave*16 + t) computed
// at k-tile t, co-issued with MFMA between the two barriers.
__global__ __launch_bounds__(256) void kC(
    const float* __restrict__ W_attn, const float* __restrict__ b_attn,
    const float* __restrict__ ws_ht,
    const unsigned short* __restrict__ encb, const unsigned short* __restrict__ wab,
    const float* __restrict__ v, float* __restrict__ spart)
{
    __shared__ unsigned short As[64 * 64];
    __shared__ unsigned short Bs[64 * 64];
    __shared__ float qsh[64], vsh[64];
    int bx = blockIdx.x, by = blockIdx.y;
    int s0 = bx * 64, h0 = by * 64;
    int tid = threadIdx.x;
    int wave = tid >> 6, lane = tid & 63;

    if (tid < 64) vsh[tid] = v[h0 + tid];

    // staging addresses (chunk-XOR swizzle; linear LDS dest)
    int r0 = tid >> 3, p0 = tid & 7;
    int lc = (p0 ^ (r0 & 7)) * 8;
    const unsigned short* aS0 = encb + (size_t)(s0 + r0) * E_ + lc;
    const unsigned short* aS1 = encb + (size_t)(s0 + 32 + r0) * E_ + lc;
    const unsigned short* bS0 = wab  + (size_t)(h0 + r0) * E_ + lc;
    const unsigned short* bS1 = wab  + (size_t)(h0 + 32 + r0) * E_ + lc;

    int wr = (wave >> 1) * 32, wc = (wave & 1) * 32;
    int fc = lane & 15, g = lane >> 4;
    int aRow[2], bRow[2], pc[2];
    #pragma unroll
    for (int m = 0; m < 2; ++m) aRow[m] = (wr + m * 16 + fc) * 64;
    #pragma unroll
    for (int n = 0; n < 2; ++n) bRow[n] = (wc + n * 16 + fc) * 64;
    #pragma unroll
    for (int kk = 0; kk < 2; ++kk) pc[kk] = ((kk * 4 + g) ^ (fc & 7)) * 8;

    f32x4 acc[2][2];
    #pragma unroll
    for (int m = 0; m < 2; ++m)
        #pragma unroll
        for (int n = 0; n < 2; ++n)
            acc[m][n] = (f32x4){0.f, 0.f, 0.f, 0.f};

    // stage tile 0
    gload16(aS0, As + tid * 8);
    gload16(aS1, As + (tid + 256) * 8);
    gload16(bS0, Bs + tid * 8);
    gload16(bS1, Bs + (tid + 256) * 8);

    #pragma unroll 1
    for (int t = 0; t < 16; ++t) {
        __syncthreads();   // tile t staged (vmcnt drained at barrier)
        #pragma unroll
        for (int kk = 0; kk < 2; ++kk) {
            bf16x8 af[2], bf2[2];
            #pragma unroll
            for (int m = 0; m < 2; ++m) af[m] = *(const bf16x8*)(As + aRow[m] + pc[kk]);
            #pragma unroll
            for (int n = 0; n < 2; ++n) bf2[n] = *(const bf16x8*)(Bs + bRow[n] + pc[kk]);
            #pragma unroll
            for (int m = 0; m < 2; ++m)
                #pragma unroll
                for (int n = 0; n < 2; ++n)
                    acc[m][n] = __builtin_amdgcn_mfma_f32_16x16x32_bf16(
                        af[m], bf2[n], acc[m][n], 0, 0, 0);
        }
        // q row for this wave, iteration t (VMEM+VALU, no LDS tile access)
        {
            int r = h0 + wave * 16 + t;
            const float* rowp = W_attn + (size_t)r * (E_ + H_);
            float qa = 0.f;
            #pragma unroll
            for (int it = 0; it < 4; ++it) {
                int idx = (lane + it * 64) * 4;
                float4 wv = *(const float4*)(rowp + idx);
                float4 hv = *(const float4*)(ws_ht + idx);
                qa = fmaf(wv.x, hv.x, qa); qa = fmaf(wv.y, hv.y, qa);
                qa = fmaf(wv.z, hv.z, qa); qa = fmaf(wv.w, hv.w, qa);
            }
            #pragma unroll
            for (int m = 32; m; m >>= 1) qa += __shfl_down(qa, m, 64);
            if (lane == 0) qsh[wave * 16 + t] = qa + b_attn[r];
        }
        __syncthreads();   // LDS reads done + qsh row visible
        if (t < 15) {
            int k0 = (t + 1) * 64;
            gload16(aS0 + k0, As + tid * 8);
            gload16(aS1 + k0, As + (tid + 256) * 8);
            gload16(bS0 + k0, Bs + tid * 8);
            gload16(bS1 + k0, Bs + (tid + 256) * 8);
        }
    }

    // ---- epilogue: partial scores ----
    float qv[2], vv[2];
    #pragma unroll
    for (int n = 0; n < 2; ++n) {
        int col = wc + n * 16 + fc;
        qv[n] = qsh[col];
        vv[n] = vsh[col];
    }
    int part = by * 2 + (wave & 1);
    #pragma unroll
    for (int m = 0; m < 2; ++m) {
        #pragma unroll
        for (int j = 0; j < 4; ++j) {
            float p = 0.f;
            #pragma unroll
            for (int n = 0; n < 2; ++n)
                p += tanhf(acc[m][n][j] + qv[n]) * vv[n];
            #pragma unroll
            for (int mask = 8; mask; mask >>= 1) p += __shfl_xor(p, mask, 64);
            if (fc == 0)
                spart[(size_t)(s0 + wr + m * 16 + g * 4 + j) * 32 + part] = p;
        }
    }
}

// ---------------- KD: e = exp(sum spart); gpart; ctxU += e * enc ----------------
// 128 blocks x 256 threads; block handles 16 s-rows. (unchanged, proven)
__global__ __launch_bounds__(256) void kD(
    const float* __restrict__ spart, const unsigned short* __restrict__ encb,
    float* __restrict__ expw, float* __restrict__ gpart, float* __restrict__ ctx)
{
    __shared__ float esh[16];
    int b = blockIdx.x, tid = threadIdx.x;
    int s0 = b * 16;
    int sl = tid >> 4, pp = tid & 15;
    float vsum = spart[(size_t)(s0 + sl) * 32 + pp]
               + spart[(size_t)(s0 + sl) * 32 + pp + 16];
    #pragma unroll
    for (int mask = 8; mask; mask >>= 1) vsum += __shfl_xor(vsum, mask, 64);
    if (pp == 0) {
        float e = expf(vsum);
        expw[s0 + sl] = e;
        esh[sl] = e;
    }
    __syncthreads();
    if (tid == 0) {
        float bs = 0.f;
        #pragma unroll
        for (int i = 0; i < 16; ++i) bs += esh[i];
        gpart[b] = bs;
    }
    int e0 = tid * 4;
    float a0 = 0.f, a1 = 0.f, a2 = 0.f, a3 = 0.f;
    #pragma unroll
    for (int ss = 0; ss < 16; ++ss) {
        ushort4 u = *(const ushort4*)(encb + (size_t)(s0 + ss) * E_ + e0);
        float w = esh[ss];
        a0 = fmaf(w, bf2f(u.x), a0);
        a1 = fmaf(w, bf2f(u.y), a1);
        a2 = fmaf(w, bf2f(u.z), a2);
        a3 = fmaf(w, bf2f(u.w), a3);
    }
    atomicAdd(&ctx[e0 + 0], a0);
    atomicAdd(&ctx[e0 + 1], a1);
    atomicAdd(&ctx[e0 + 2], a2);
    atomicAdd(&ctx[e0 + 3], a3);
}

// ---------------- KE: ht_tilda (blocks 0..255, wave-per-row) ; out_w (256..257) ----------------
__global__ __launch_bounds__(256) void kE(
    const float* __restrict__ W_ah, const float* __restrict__ b_ah,
    const float* __restrict__ ctx, const float* __restrict__ ht,
    const float* __restrict__ gpart, const float* __restrict__ expw,
    float* __restrict__ out_htt, float* __restrict__ ws_htt,
    float* __restrict__ out_w)
{
    int b = blockIdx.x;
    int wave = threadIdx.x >> 6, lane = threadIdx.x & 63;
    float gsum = gpart[lane] + gpart[lane + 64];
    #pragma unroll
    for (int m = 32; m; m >>= 1) gsum += __shfl_xor(gsum, m, 64);
    float invS = 1.0f / gsum;
    if (b >= 256) {
        int s = (b - 256) * 1024 + (int)threadIdx.x * 4;
        float4 e4 = *(const float4*)(expw + s);
        float4 w4 = { e4.x * invS, e4.y * invS, e4.z * invS, e4.w * invS };
        *(float4*)(out_w + s) = w4;
        return;
    }
    int r = b * 4 + wave;
    const float* row = W_ah + (size_t)r * (E_ + H_);
    float acc = 0.f;
    #pragma unroll
    for (int it = 0; it < 8; ++it) {
        int idx = (lane + it * 64) * 4;
        f32x4 wv = ntload4(row + idx);
        float4 xv;
        if (idx < E_) {
            float4 cv = *(const float4*)(ctx + idx);
            xv = (float4){ cv.x * invS, cv.y * invS, cv.z * invS, cv.w * invS };
        } else {
            xv = *(const float4*)(ht + idx - E_);
        }
        acc = fmaf(wv[0], xv.x, acc); acc = fmaf(wv[1], xv.y, acc);
        acc = fmaf(wv[2], xv.z, acc); acc = fmaf(wv[3], xv.w, acc);
    }
    #pragma unroll
    for (int m = 32; m; m >>= 1) acc += __shfl_down(acc, m, 64);
    if (lane == 0) {
        float val = tanhf(acc + b_ah[r]);
        out_htt[r] = val;
        ws_htt[r]  = val;
    }
}

// ---------------- KF: logits (4 rows/wave, nt loads) + per-block expsum ----------------
// 2000 blocks x 256 thr; 16 rows/block.
__global__ __launch_bounds__(256) void kF(
    const float* __restrict__ W_out, const float* __restrict__ b_out,
    const float* __restrict__ ht_tilda, float* __restrict__ logits,
    float* __restrict__ lpart)
{
    __shared__ float wes[4];
    int b = blockIdx.x;
    int wave = threadIdx.x >> 6, lane = threadIdx.x & 63;
    int r0 = b * 16 + wave * 4;
    const float* w0 = W_out + (size_t)r0 * H_;
    const float* w1 = W_out + (size_t)(r0 + 1) * H_;
    const float* w2 = W_out + (size_t)(r0 + 2) * H_;
    const float* w3 = W_out + (size_t)(r0 + 3) * H_;
    float a0 = 0.f, a1 = 0.f, a2 = 0.f, a3 = 0.f;
    #pragma unroll
    for (int it = 0; it < 4; ++it) {
        int idx = (lane + it * 64) * 4;
        float4 hv = *(const float4*)(ht_tilda + idx);
        f32x4 v0 = ntload4(w0 + idx);
        f32x4 v1 = ntload4(w1 + idx);
        f32x4 v2 = ntload4(w2 + idx);
        f32x4 v3 = ntload4(w3 + idx);
        a0 = fmaf(v0[0], hv.x, a0); a0 = fmaf(v0[1], hv.y, a0);
        a0 = fmaf(v0[2], hv.z, a0); a0 = fmaf(v0[3], hv.w, a0);
        a1 = fmaf(v1[0], hv.x, a1); a1 = fmaf(v1[1], hv.y, a1);
        a1 = fmaf(v1[2], hv.z, a1); a1 = fmaf(v1[3], hv.w, a1);
        a2 = fmaf(v2[0], hv.x, a2); a2 = fmaf(v2[1], hv.y, a2);
        a2 = fmaf(v2[2], hv.z, a2); a2 = fmaf(v2[3], hv.w, a2);
        a3 = fmaf(v3[0], hv.x, a3); a3 = fmaf(v3[1], hv.y, a3);
        a3 = fmaf(v3[2], hv.z, a3); a3 = fmaf(v3[3], hv.w, a3);
    }
    #pragma unroll
    for (int m = 32; m; m >>= 1) {
        a0 += __shfl_down(a0, m, 64); a1 += __shfl_down(a1, m, 64);
        a2 += __shfl_down(a2, m, 64); a3 += __shfl_down(a3, m, 64);
    }
    if (lane == 0) {
        float lg0 = a0 + b_out[r0];
        float lg1 = a1 + b_out[r0 + 1];
        float lg2 = a2 + b_out[r0 + 2];
        float lg3 = a3 + b_out[r0 + 3];
        logits[r0]     = lg0;
        logits[r0 + 1] = lg1;
        logits[r0 + 2] = lg2;
        logits[r0 + 3] = lg3;
        wes[wave] = expf(lg0) + expf(lg1) + expf(lg2) + expf(lg3);
    }
    __syncthreads();
    if (threadIdx.x == 0)
        lpart[b] = wes[0] + wes[1] + wes[2] + wes[3];
}

// ---------------- KG: lse (redundant x8) + subtract ----------------
// 8 blocks x 1024 thr; each block handles 4000 logit rows.
__global__ __launch_bounds__(1024) void kG(
    float* __restrict__ out, const float* __restrict__ lpart)
{
    __shared__ float sred[16];
    int b = blockIdx.x, tid = threadIdx.x;
    float s = 0.f;
    #pragma unroll
    for (int k = 0; k < 2; ++k) {
        int i = tid + k * 1024;
        if (i < 2000) s += lpart[i];
    }
    #pragma unroll
    for (int m = 32; m; m >>= 1) s += __shfl_down(s, m, 64);
    if ((tid & 63) == 0) sred[tid >> 6] = s;
    __syncthreads();
    float tot = 0.f;
    #pragma unroll
    for (int i = 0; i < 16; ++i) tot += sred[i];
    float lse = logf(tot);
    #pragma unroll
    for (int k = 0; k < 4; ++k) {
        int row = b * 4000 + k * 1024 + tid;
        if (row < (b + 1) * 4000 && row < V_) out[row] -= lse;
    }
}

extern "C" void kernel_launch(void* const* d_in, const int* in_sizes, int n_in,
                              void* d_out, int out_size, void* d_ws, size_t ws_size,
                              hipStream_t stream) {
    const float* enc          = (const float*)d_in[0];
    const int*   word         = (const int*)  d_in[1];
    const float* last_context = (const float*)d_in[2];
    const float* h0           = (const float*)d_in[3];
    const float* c0           = (const float*)d_in[4];
    const float* emb          = (const float*)d_in[5];
    const float* W_ih         = (const float*)d_in[6];
    const float* W_hh         = (const float*)d_in[7];
    const float* b_ih         = (const float*)d_in[8];
    const float* b_hh         = (const float*)d_in[9];
    const float* W_attn       = (const float*)d_in[10];
    const float* b_attn       = (const float*)d_in[11];
    const float* v            = (const float*)d_in[12];
    const float* W_ah         = (const float*)d_in[13];
    const float* b_ah         = (const float*)d_in[14];
    const float* W_out        = (const float*)d_in[15];
    const float* b_out        = (const float*)d_in[16];

    float* out        = (float*)d_out;
    float* out_logits = out;                 // 32000
    float* out_ht     = out + V_;            // 1024
    float* out_c      = out + V_ + H_;       // 1024
    float* out_htt    = out + V_ + 2 * H_;   // 1024
    float* out_w      = out + V_ + 3 * H_;   // 2048

    float* ws      = (float*)d_ws;
    float* ws_ht   = ws;             // 1024
    float* ws_expw = ws + 1024;      // 2048
    float* ws_ctx  = ws + 3072;      // 1024
    float* ws_gp   = ws + 4096;      // 128
    float* ws_htt  = ws + 4224;      // 1024
    float* ws_lp   = ws + 5248;      // 2000
    float* ws_sp   = ws + 16384;     // 2048*32
    unsigned short* encb = (unsigned short*)(ws + 81920);  // 2048*1024 bf16
    unsigned short* wab  = encb + (size_t)S_ * E_;         // 1024*1024 bf16

    kA<<<1536, 256, 0, stream>>>(W_ih, W_hh, b_ih, b_hh, last_context, emb, word,
                                 h0, c0, enc, W_attn, out_ht, out_c, ws_ht,
                                 encb, wab, ws_ctx);
    kC<<<dim3(32, 16), 256, 0, stream>>>(W_attn, b_attn, ws_ht, encb, wab, v, ws_sp);
    kD<<<128, 256, 0, stream>>>(ws_sp, encb, ws_expw, ws_gp, ws_ctx);
    kE<<<258, 256, 0, stream>>>(W_ah, b_ah, ws_ctx, ws_ht, ws_gp, ws_expw,
                                out_htt, ws_htt, out_w);
    kF<<<2000, 256, 0, stream>>>(W_out, b_out, ws_htt, out_logits, ws_lp);
    kG<<<8, 1024, 0, stream>>>(out_logits, ws_lp);
}

// Round 10
// 82.200 us; speedup vs baseline: 1.1242x; 1.1242x over previous
//
#include <hip/hip_runtime.h>
#include <math.h>

#define V_ 32000
#define E_ 1024
#define H_ 1024
#define S_ 2048

typedef __attribute__((ext_vector_type(8))) short bf16x8;
typedef __attribute__((ext_vector_type(8))) unsigned short u16x8;
typedef __attribute__((ext_vector_type(4))) float f32x4;

typedef __attribute__((address_space(1))) const unsigned int gu32;
typedef __attribute__((address_space(3))) unsigned int lu32;

__device__ __forceinline__ float sigmoidf_(float x) { return 1.0f / (1.0f + expf(-x)); }

__device__ __forceinline__ unsigned short f2bf(float f) {
    unsigned int u = __builtin_bit_cast(unsigned int, f);
    unsigned int r = (u + 0x7fffu + ((u >> 16) & 1u)) >> 16;
    return (unsigned short)r;
}
__device__ __forceinline__ float bf2f(unsigned short u) {
    return __builtin_bit_cast(float, ((unsigned int)u) << 16);
}
__device__ __forceinline__ u16x8 pack8(float4 a, float4 b) {
    u16x8 p;
    p[0] = f2bf(a.x); p[1] = f2bf(a.y); p[2] = f2bf(a.z); p[3] = f2bf(a.w);
    p[4] = f2bf(b.x); p[5] = f2bf(b.y); p[6] = f2bf(b.z); p[7] = f2bf(b.w);
    return p;
}
__device__ __forceinline__ void gload16(const void* g, void* l) {
    __builtin_amdgcn_global_load_lds((gu32*)g, (lu32*)l, 16, 0, 0);
}

// ---------------- KA: LSTM (blocks 0..1023) || bf16 conversion (1024..1535) ----------------
__global__ __launch_bounds__(256) void kA(
    const float* __restrict__ W_ih, const float* __restrict__ W_hh,
    const float* __restrict__ b_ih, const float* __restrict__ b_hh,
    const float* __restrict__ last_context, const float* __restrict__ emb,
    const int* __restrict__ word, const float* __restrict__ h0,
    const float* __restrict__ c0, const float* __restrict__ enc,
    const float* __restrict__ W_attn,
    float* __restrict__ out_ht, float* __restrict__ out_c,
    float* __restrict__ ws_ht, unsigned short* __restrict__ encb,
    unsigned short* __restrict__ wab, float* __restrict__ ws_ctx)
{
    int b = blockIdx.x, tid = threadIdx.x;
    int wave = tid >> 6, lane = tid & 63;
    if (b < 1024) {
        __shared__ float sbuf[4];
        int j = b;
        const float* embrow = emb + (size_t)word[0] * E_;
        int row = j + wave * H_;
        const float* wi = W_ih + (size_t)row * (E_ + H_);
        const float* wh = W_hh + (size_t)row * H_;
        float acc = 0.f;
        #pragma unroll
        for (int it = 0; it < 8; ++it) {
            int idx = (lane + it * 64) * 4;
            float4 wv = *(const float4*)(wi + idx);
            float4 xv = (idx < H_) ? *(const float4*)(last_context + idx)
                                   : *(const float4*)(embrow + (idx - H_));
            acc = fmaf(wv.x, xv.x, acc); acc = fmaf(wv.y, xv.y, acc);
            acc = fmaf(wv.z, xv.z, acc); acc = fmaf(wv.w, xv.w, acc);
        }
        #pragma unroll
        for (int it = 0; it < 4; ++it) {
            int idx = (lane + it * 64) * 4;
            float4 wv = *(const float4*)(wh + idx);
            float4 hv = *(const float4*)(h0 + idx);
            acc = fmaf(wv.x, hv.x, acc); acc = fmaf(wv.y, hv.y, acc);
            acc = fmaf(wv.z, hv.z, acc); acc = fmaf(wv.w, hv.w, acc);
        }
        #pragma unroll
        for (int m = 32; m; m >>= 1) acc += __shfl_down(acc, m, 64);
        if (lane == 0) sbuf[wave] = acc;
        __syncthreads();
        if (tid == 0) {
            float gi = sbuf[0] + b_ih[j]          + b_hh[j];
            float gf = sbuf[1] + b_ih[j + H_]     + b_hh[j + H_];
            float gg = sbuf[2] + b_ih[j + 2*H_]   + b_hh[j + 2*H_];
            float go = sbuf[3] + b_ih[j + 3*H_]   + b_hh[j + 3*H_];
            float c  = sigmoidf_(gf) * c0[j] + sigmoidf_(gi) * tanhf(gg);
            float ht = sigmoidf_(go) * tanhf(c);
            out_c[j]  = c;
            out_ht[j] = ht;
            ws_ht[j]  = ht;
        }
        if (b == 0) {
            ws_ctx[tid]       = 0.f;
            ws_ctx[tid + 256] = 0.f;
            ws_ctx[tid + 512] = 0.f;
            ws_ctx[tid + 768] = 0.f;
        }
    } else {
        int cid = (b - 1024) * 256 + tid;
        const int ENC_CH = (S_ * E_) / 8;   // 262144
        #pragma unroll
        for (int i = 0; i < 3; ++i) {
            int idx = cid + i * 131072;
            const float* src;
            unsigned short* dst;
            if (idx < ENC_CH) {
                src = enc + (size_t)idx * 8;
                dst = encb + (size_t)idx * 8;
            } else {
                int w = idx - ENC_CH;
                int h = w >> 7, off = (w & 127) * 8;
                src = W_attn + (size_t)h * (E_ + H_) + H_ + off;
                dst = wab + (size_t)h * E_ + off;
            }
            float4 a = *(const float4*)src;
            float4 bq = *(const float4*)(src + 4);
            *(u16x8*)dst = pack8(a, bq);
        }
    }
}

// ---------------- KC: q-prologue (batched, staged under tile-0) + scores GEMM ----------------
// grid (32,16) = 512 blocks, 256 thr = 4 waves (2x2; wave tile 32x32).
__global__ __launch_bounds__(256) void kC(
    const float* __restrict__ W_attn, const float* __restrict__ b_attn,
    const float* __restrict__ ws_ht,
    const unsigned short* __restrict__ encb, const unsigned short* __restrict__ wab,
    const float* __restrict__ v, float* __restrict__ spart)
{
    __shared__ unsigned short As[64 * 64];
    __shared__ unsigned short Bs[64 * 64];
    __shared__ float qsh[64], vsh[64];
    int bx = blockIdx.x, by = blockIdx.y;
    int s0 = bx * 64, h0 = by * 64;
    int tid = threadIdx.x;
    int wave = tid >> 6, lane = tid & 63;

    // staging addresses (chunk-XOR swizzle; linear LDS dest)
    int r0 = tid >> 3, p0 = tid & 7;
    int lc = (p0 ^ (r0 & 7)) * 8;
    const unsigned short* aS0 = encb + (size_t)(s0 + r0) * E_ + lc;
    const unsigned short* aS1 = encb + (size_t)(s0 + 32 + r0) * E_ + lc;
    const unsigned short* bS0 = wab  + (size_t)(h0 + r0) * E_ + lc;
    const unsigned short* bS1 = wab  + (size_t)(h0 + 32 + r0) * E_ + lc;

    // stage tile 0 first — its latency hides under the q-prologue
    gload16(aS0, As + tid * 8);
    gload16(aS1, As + (tid + 256) * 8);
    gload16(bS0, Bs + tid * 8);
    gload16(bS1, Bs + (tid + 256) * 8);

    // ---- q prologue: 4 batches x 4 rows per wave (independent loads -> MLP) ----
    {
        float4 hv[4];
        #pragma unroll
        for (int it = 0; it < 4; ++it)
            hv[it] = *(const float4*)(ws_ht + (lane + it * 64) * 4);
        #pragma unroll 1
        for (int bq = 0; bq < 4; ++bq) {
            int rbase = h0 + wave * 16 + bq * 4;
            float qa[4];
            #pragma unroll
            for (int rr = 0; rr < 4; ++rr) {
                const float* rowp = W_attn + (size_t)(rbase + rr) * (E_ + H_);
                float a = 0.f;
                #pragma unroll
                for (int it = 0; it < 4; ++it) {
                    float4 wv = *(const float4*)(rowp + (lane + it * 64) * 4);
                    a = fmaf(wv.x, hv[it].x, a); a = fmaf(wv.y, hv[it].y, a);
                    a = fmaf(wv.z, hv[it].z, a); a = fmaf(wv.w, hv[it].w, a);
                }
                qa[rr] = a;
            }
            #pragma unroll
            for (int rr = 0; rr < 4; ++rr) {
                #pragma unroll
                for (int m = 32; m; m >>= 1) qa[rr] += __shfl_down(qa[rr], m, 64);
            }
            if (lane == 0) {
                #pragma unroll
                for (int rr = 0; rr < 4; ++rr)
                    qsh[wave * 16 + bq * 4 + rr] = qa[rr] + b_attn[rbase + rr];
            }
        }
    }
    if (tid < 64) vsh[tid] = v[h0 + tid];

    int wr = (wave >> 1) * 32, wc = (wave & 1) * 32;
    int fc = lane & 15, g = lane >> 4;
    int aRow[2], bRow[2], pc[2];
    #pragma unroll
    for (int m = 0; m < 2; ++m) aRow[m] = (wr + m * 16 + fc) * 64;
    #pragma unroll
    for (int n = 0; n < 2; ++n) bRow[n] = (wc + n * 16 + fc) * 64;
    #pragma unroll
    for (int kk = 0; kk < 2; ++kk) pc[kk] = ((kk * 4 + g) ^ (fc & 7)) * 8;

    f32x4 acc[2][2];
    #pragma unroll
    for (int m = 0; m < 2; ++m)
        #pragma unroll
        for (int n = 0; n < 2; ++n)
            acc[m][n] = (f32x4){0.f, 0.f, 0.f, 0.f};

    #pragma unroll 1
    for (int t = 0; t < 16; ++t) {
        __syncthreads();   // tile t staged
        #pragma unroll
        for (int kk = 0; kk < 2; ++kk) {
            bf16x8 af[2], bf2[2];
            #pragma unroll
            for (int m = 0; m < 2; ++m) af[m] = *(const bf16x8*)(As + aRow[m] + pc[kk]);
            #pragma unroll
            for (int n = 0; n < 2; ++n) bf2[n] = *(const bf16x8*)(Bs + bRow[n] + pc[kk]);
            #pragma unroll
            for (int m = 0; m < 2; ++m)
                #pragma unroll
                for (int n = 0; n < 2; ++n)
                    acc[m][n] = __builtin_amdgcn_mfma_f32_16x16x32_bf16(
                        af[m], bf2[n], acc[m][n], 0, 0, 0);
        }
        __syncthreads();   // LDS reads done
        if (t < 15) {
            int k0 = (t + 1) * 64;
            gload16(aS0 + k0, As + tid * 8);
            gload16(aS1 + k0, As + (tid + 256) * 8);
            gload16(bS0 + k0, Bs + tid * 8);
            gload16(bS1 + k0, Bs + (tid + 256) * 8);
        }
    }

    // ---- epilogue: partial scores ----
    float qv[2], vv[2];
    #pragma unroll
    for (int n = 0; n < 2; ++n) {
        int col = wc + n * 16 + fc;
        qv[n] = qsh[col];
        vv[n] = vsh[col];
    }
    int part = by * 2 + (wave & 1);
    #pragma unroll
    for (int m = 0; m < 2; ++m) {
        #pragma unroll
        for (int j = 0; j < 4; ++j) {
            float p = 0.f;
            #pragma unroll
            for (int n = 0; n < 2; ++n)
                p += tanhf(acc[m][n][j] + qv[n]) * vv[n];
            #pragma unroll
            for (int mask = 8; mask; mask >>= 1) p += __shfl_xor(p, mask, 64);
            if (fc == 0)
                spart[(size_t)(s0 + wr + m * 16 + g * 4 + j) * 32 + part] = p;
        }
    }
}

// ---------------- KD: e = exp(sum spart); gpart; ctxU += e * enc ----------------
__global__ __launch_bounds__(256) void kD(
    const float* __restrict__ spart, const unsigned short* __restrict__ encb,
    float* __restrict__ expw, float* __restrict__ gpart, float* __restrict__ ctx)
{
    __shared__ float esh[16];
    int b = blockIdx.x, tid = threadIdx.x;
    int s0 = b * 16;
    int sl = tid >> 4, pp = tid & 15;
    float vsum = spart[(size_t)(s0 + sl) * 32 + pp]
               + spart[(size_t)(s0 + sl) * 32 + pp + 16];
    #pragma unroll
    for (int mask = 8; mask; mask >>= 1) vsum += __shfl_xor(vsum, mask, 64);
    if (pp == 0) {
        float e = expf(vsum);
        expw[s0 + sl] = e;
        esh[sl] = e;
    }
    __syncthreads();
    if (tid == 0) {
        float bs = 0.f;
        #pragma unroll
        for (int i = 0; i < 16; ++i) bs += esh[i];
        gpart[b] = bs;
    }
    int e0 = tid * 4;
    float a0 = 0.f, a1 = 0.f, a2 = 0.f, a3 = 0.f;
    #pragma unroll
    for (int ss = 0; ss < 16; ++ss) {
        ushort4 u = *(const ushort4*)(encb + (size_t)(s0 + ss) * E_ + e0);
        float w = esh[ss];
        a0 = fmaf(w, bf2f(u.x), a0);
        a1 = fmaf(w, bf2f(u.y), a1);
        a2 = fmaf(w, bf2f(u.z), a2);
        a3 = fmaf(w, bf2f(u.w), a3);
    }
    atomicAdd(&ctx[e0 + 0], a0);
    atomicAdd(&ctx[e0 + 1], a1);
    atomicAdd(&ctx[e0 + 2], a2);
    atomicAdd(&ctx[e0 + 3], a3);
}

// ---------------- KE: ht_tilda (blocks 0..255, wave-per-row) ; out_w (256..257) ----------------
__global__ __launch_bounds__(256) void kE(
    const float* __restrict__ W_ah, const float* __restrict__ b_ah,
    const float* __restrict__ ctx, const float* __restrict__ ht,
    const float* __restrict__ gpart, const float* __restrict__ expw,
    float* __restrict__ out_htt, float* __restrict__ ws_htt,
    float* __restrict__ out_w)
{
    int b = blockIdx.x;
    int wave = threadIdx.x >> 6, lane = threadIdx.x & 63;
    float gsum = gpart[lane] + gpart[lane + 64];
    #pragma unroll
    for (int m = 32; m; m >>= 1) gsum += __shfl_xor(gsum, m, 64);
    float invS = 1.0f / gsum;
    if (b >= 256) {
        int s = (b - 256) * 1024 + (int)threadIdx.x * 4;
        float4 e4 = *(const float4*)(expw + s);
        float4 w4 = { e4.x * invS, e4.y * invS, e4.z * invS, e4.w * invS };
        *(float4*)(out_w + s) = w4;
        return;
    }
    int r = b * 4 + wave;
    const float* row = W_ah + (size_t)r * (E_ + H_);
    float acc = 0.f;
    #pragma unroll
    for (int it = 0; it < 8; ++it) {
        int idx = (lane + it * 64) * 4;
        float4 wv = *(const float4*)(row + idx);
        float4 xv;
        if (idx < E_) {
            float4 cv = *(const float4*)(ctx + idx);
            xv = (float4){ cv.x * invS, cv.y * invS, cv.z * invS, cv.w * invS };
        } else {
            xv = *(const float4*)(ht + idx - E_);
        }
        acc = fmaf(wv.x, xv.x, acc); acc = fmaf(wv.y, xv.y, acc);
        acc = fmaf(wv.z, xv.z, acc); acc = fmaf(wv.w, xv.w, acc);
    }
    #pragma unroll
    for (int m = 32; m; m >>= 1) acc += __shfl_down(acc, m, 64);
    if (lane == 0) {
        float val = tanhf(acc + b_ah[r]);
        out_htt[r] = val;
        ws_htt[r]  = val;
    }
}

// ---------------- KF: logits (4 rows/wave) + per-block expsum ----------------
// 2000 blocks x 256 thr; 16 rows/block.
__global__ __launch_bounds__(256) void kF(
    const float* __restrict__ W_out, const float* __restrict__ b_out,
    const float* __restrict__ ht_tilda, float* __restrict__ logits,
    float* __restrict__ lpart)
{
    __shared__ float wes[4];
    int b = blockIdx.x;
    int wave = threadIdx.x >> 6, lane = threadIdx.x & 63;
    int r0 = b * 16 + wave * 4;
    const float* w0 = W_out + (size_t)r0 * H_;
    const float* w1 = W_out + (size_t)(r0 + 1) * H_;
    const float* w2 = W_out + (size_t)(r0 + 2) * H_;
    const float* w3 = W_out + (size_t)(r0 + 3) * H_;
    float a0 = 0.f, a1 = 0.f, a2 = 0.f, a3 = 0.f;
    #pragma unroll
    for (int it = 0; it < 4; ++it) {
        int idx = (lane + it * 64) * 4;
        float4 hv = *(const float4*)(ht_tilda + idx);
        float4 v0 = *(const float4*)(w0 + idx);
        float4 v1 = *(const float4*)(w1 + idx);
        float4 v2 = *(const float4*)(w2 + idx);
        float4 v3 = *(const float4*)(w3 + idx);
        a0 = fmaf(v0.x, hv.x, a0); a0 = fmaf(v0.y, hv.y, a0);
        a0 = fmaf(v0.z, hv.z, a0); a0 = fmaf(v0.w, hv.w, a0);
        a1 = fmaf(v1.x, hv.x, a1); a1 = fmaf(v1.y, hv.y, a1);
        a1 = fmaf(v1.z, hv.z, a1); a1 = fmaf(v1.w, hv.w, a1);
        a2 = fmaf(v2.x, hv.x, a2); a2 = fmaf(v2.y, hv.y, a2);
        a2 = fmaf(v2.z, hv.z, a2); a2 = fmaf(v2.w, hv.w, a2);
        a3 = fmaf(v3.x, hv.x, a3); a3 = fmaf(v3.y, hv.y, a3);
        a3 = fmaf(v3.z, hv.z, a3); a3 = fmaf(v3.w, hv.w, a3);
    }
    #pragma unroll
    for (int m = 32; m; m >>= 1) {
        a0 += __shfl_down(a0, m, 64); a1 += __shfl_down(a1, m, 64);
        a2 += __shfl_down(a2, m, 64); a3 += __shfl_down(a3, m, 64);
    }
    if (lane == 0) {
        float lg0 = a0 + b_out[r0];
        float lg1 = a1 + b_out[r0 + 1];
        float lg2 = a2 + b_out[r0 + 2];
        float lg3 = a3 + b_out[r0 + 3];
        logits[r0]     = lg0;
        logits[r0 + 1] = lg1;
        logits[r0 + 2] = lg2;
        logits[r0 + 3] = lg3;
        wes[wave] = expf(lg0) + expf(lg1) + expf(lg2) + expf(lg3);
    }
    __syncthreads();
    if (threadIdx.x == 0)
        lpart[b] = wes[0] + wes[1] + wes[2] + wes[3];
}

// ---------------- KG: lse (redundant x8) + subtract ----------------
__global__ __launch_bounds__(1024) void kG(
    float* __restrict__ out, const float* __restrict__ lpart)
{
    __shared__ float sred[16];
    int b = blockIdx.x, tid = threadIdx.x;
    float s = 0.f;
    #pragma unroll
    for (int k = 0; k < 2; ++k) {
        int i = tid + k * 1024;
        if (i < 2000) s += lpart[i];
    }
    #pragma unroll
    for (int m = 32; m; m >>= 1) s += __shfl_down(s, m, 64);
    if ((tid & 63) == 0) sred[tid >> 6] = s;
    __syncthreads();
    float tot = 0.f;
    #pragma unroll
    for (int i = 0; i < 16; ++i) tot += sred[i];
    float lse = logf(tot);
    #pragma unroll
    for (int k = 0; k < 4; ++k) {
        int row = b * 4000 + k * 1024 + tid;
        if (row < (b + 1) * 4000 && row < V_) out[row] -= lse;
    }
}

extern "C" void kernel_launch(void* const* d_in, const int* in_sizes, int n_in,
                              void* d_out, int out_size, void* d_ws, size_t ws_size,
                              hipStream_t stream) {
    const float* enc          = (const float*)d_in[0];
    const int*   word         = (const int*)  d_in[1];
    const float* last_context = (const float*)d_in[2];
    const float* h0           = (const float*)d_in[3];
    const float* c0           = (const float*)d_in[4];
    const float* emb          = (const float*)d_in[5];
    const float* W_ih         = (const float*)d_in[6];
    const float* W_hh         = (const float*)d_in[7];
    const float* b_ih         = (const float*)d_in[8];
    const float* b_hh         = (const float*)d_in[9];
    const float* W_attn       = (const float*)d_in[10];
    const float* b_attn       = (const float*)d_in[11];
    const float* v            = (const float*)d_in[12];
    const float* W_ah         = (const float*)d_in[13];
    const float* b_ah         = (const float*)d_in[14];
    const float* W_out        = (const float*)d_in[15];
    const float* b_out        = (const float*)d_in[16];

    float* out        = (float*)d_out;
    float* out_logits = out;                 // 32000
    float* out_ht     = out + V_;            // 1024
    float* out_c      = out + V_ + H_;       // 1024
    float* out_htt    = out + V_ + 2 * H_;   // 1024
    float* out_w      = out + V_ + 3 * H_;   // 2048

    float* ws      = (float*)d_ws;
    float* ws_ht   = ws;             // 1024
    float* ws_expw = ws + 1024;      // 2048
    float* ws_ctx  = ws + 3072;      // 1024
    float* ws_gp   = ws + 4096;      // 128
    float* ws_htt  = ws + 4224;      // 1024
    float* ws_lp   = ws + 5248;      // 2000
    float* ws_sp   = ws + 16384;     // 2048*32
    unsigned short* encb = (unsigned short*)(ws + 81920);  // 2048*1024 bf16
    unsigned short* wab  = encb + (size_t)S_ * E_;         // 1024*1024 bf16

    kA<<<1536, 256, 0, stream>>>(W_ih, W_hh, b_ih, b_hh, last_context, emb, word,
                                 h0, c0, enc, W_attn, out_ht, out_c, ws_ht,
                                 encb, wab, ws_ctx);
    kC<<<dim3(32, 16), 256, 0, stream>>>(W_attn, b_attn, ws_ht, encb, wab, v, ws_sp);
    kD<<<128, 256, 0, stream>>>(ws_sp, encb, ws_expw, ws_gp, ws_ctx);
    kE<<<258, 256, 0, stream>>>(W_ah, b_ah, ws_ctx, ws_ht, ws_gp, ws_expw,
                                out_htt, ws_htt, out_w);
    kF<<<2000, 256, 0, stream>>>(W_out, b_out, ws_htt, out_logits, ws_lp);
    kG<<<8, 1024, 0, stream>>>(out_logits, ws_lp);
}

// Round 11
// 75.055 us; speedup vs baseline: 1.2312x; 1.0952x over previous
//
#include <hip/hip_runtime.h>
#include <math.h>

#define V_ 32000
#define E_ 1024
#define H_ 1024
#define S_ 2048

typedef __attribute__((ext_vector_type(8))) short bf16x8;
typedef __attribute__((ext_vector_type(8))) unsigned short u16x8;
typedef __attribute__((ext_vector_type(4))) float f32x4;

typedef __attribute__((address_space(1))) const unsigned int gu32;
typedef __attribute__((address_space(3))) unsigned int lu32;

__device__ __forceinline__ float sigmoidf_(float x) { return 1.0f / (1.0f + expf(-x)); }

__device__ __forceinline__ unsigned short f2bf(float f) {
    unsigned int u = __builtin_bit_cast(unsigned int, f);
    unsigned int r = (u + 0x7fffu + ((u >> 16) & 1u)) >> 16;
    return (unsigned short)r;
}
__device__ __forceinline__ float bf2f(unsigned short u) {
    return __builtin_bit_cast(float, ((unsigned int)u) << 16);
}
__device__ __forceinline__ u16x8 pack8(float4 a, float4 b) {
    u16x8 p;
    p[0] = f2bf(a.x); p[1] = f2bf(a.y); p[2] = f2bf(a.z); p[3] = f2bf(a.w);
    p[4] = f2bf(b.x); p[5] = f2bf(b.y); p[6] = f2bf(b.z); p[7] = f2bf(b.w);
    return p;
}
__device__ __forceinline__ void gload16(const void* g, void* l) {
    __builtin_amdgcn_global_load_lds((gu32*)g, (lu32*)l, 16, 0, 0);
}

// ---------------- KA: LSTM (blocks 0..1023) || bf16 conversion (1024..1535) ----------------
__global__ __launch_bounds__(256) void kA(
    const float* __restrict__ W_ih, const float* __restrict__ W_hh,
    const float* __restrict__ b_ih, const float* __restrict__ b_hh,
    const float* __restrict__ last_context, const float* __restrict__ emb,
    const int* __restrict__ word, const float* __restrict__ h0,
    const float* __restrict__ c0, const float* __restrict__ enc,
    const float* __restrict__ W_attn,
    float* __restrict__ out_ht, float* __restrict__ out_c,
    float* __restrict__ ws_ht, unsigned short* __restrict__ encb,
    unsigned short* __restrict__ wab, float* __restrict__ ws_ctx)
{
    int b = blockIdx.x, tid = threadIdx.x;
    int wave = tid >> 6, lane = tid & 63;
    if (b < 1024) {
        __shared__ float sbuf[4];
        int j = b;
        const float* embrow = emb + (size_t)word[0] * E_;
        int row = j + wave * H_;
        const float* wi = W_ih + (size_t)row * (E_ + H_);
        const float* wh = W_hh + (size_t)row * H_;
        float acc = 0.f;
        #pragma unroll
        for (int it = 0; it < 8; ++it) {
            int idx = (lane + it * 64) * 4;
            float4 wv = *(const float4*)(wi + idx);
            float4 xv = (idx < H_) ? *(const float4*)(last_context + idx)
                                   : *(const float4*)(embrow + (idx - H_));
            acc = fmaf(wv.x, xv.x, acc); acc = fmaf(wv.y, xv.y, acc);
            acc = fmaf(wv.z, xv.z, acc); acc = fmaf(wv.w, xv.w, acc);
        }
        // h0 contribution: skip the W_hh read entirely when h0 == 0 (bit-exact:
        // finite W_hh * 0 adds exactly 0). General: branch taken if any nonzero.
        {
            float4 hvv[4];
            int nz = 0;
            #pragma unroll
            for (int it = 0; it < 4; ++it) {
                hvv[it] = *(const float4*)(h0 + (lane + it * 64) * 4);
                nz |= (hvv[it].x != 0.f) | (hvv[it].y != 0.f) |
                      (hvv[it].z != 0.f) | (hvv[it].w != 0.f);
            }
            if (__any(nz)) {
                #pragma unroll
                for (int it = 0; it < 4; ++it) {
                    int idx = (lane + it * 64) * 4;
                    float4 wv = *(const float4*)(wh + idx);
                    acc = fmaf(wv.x, hvv[it].x, acc); acc = fmaf(wv.y, hvv[it].y, acc);
                    acc = fmaf(wv.z, hvv[it].z, acc); acc = fmaf(wv.w, hvv[it].w, acc);
                }
            }
        }
        #pragma unroll
        for (int m = 32; m; m >>= 1) acc += __shfl_down(acc, m, 64);
        if (lane == 0) sbuf[wave] = acc;
        __syncthreads();
        if (tid == 0) {
            float gi = sbuf[0] + b_ih[j]          + b_hh[j];
            float gf = sbuf[1] + b_ih[j + H_]     + b_hh[j + H_];
            float gg = sbuf[2] + b_ih[j + 2*H_]   + b_hh[j + 2*H_];
            float go = sbuf[3] + b_ih[j + 3*H_]   + b_hh[j + 3*H_];
            float c  = sigmoidf_(gf) * c0[j] + sigmoidf_(gi) * tanhf(gg);
            float ht = sigmoidf_(go) * tanhf(c);
            out_c[j]  = c;
            out_ht[j] = ht;
            ws_ht[j]  = ht;
        }
        if (b == 0) {
            #pragma unroll
            for (int i = 0; i < 16; ++i)
                ws_ctx[tid + i * 256] = 0.f;   // 4 copies x 1024
        }
    } else {
        int cid = (b - 1024) * 256 + tid;
        const int ENC_CH = (S_ * E_) / 8;   // 262144
        #pragma unroll
        for (int i = 0; i < 3; ++i) {
            int idx = cid + i * 131072;
            const float* src;
            unsigned short* dst;
            if (idx < ENC_CH) {
                src = enc + (size_t)idx * 8;
                dst = encb + (size_t)idx * 8;
            } else {
                int w = idx - ENC_CH;
                int h = w >> 7, off = (w & 127) * 8;
                src = W_attn + (size_t)h * (E_ + H_) + H_ + off;
                dst = wab + (size_t)h * E_ + off;
            }
            float4 a = *(const float4*)src;
            float4 bq = *(const float4*)(src + 4);
            *(u16x8*)dst = pack8(a, bq);
        }
    }
}

// ---------------- KC: q-prologue + double-buffered scores GEMM ----------------
// grid (32,16) = 512 blocks, 256 thr = 4 waves (2x2; wave tile 32x32).
__global__ __launch_bounds__(256) void kC(
    const float* __restrict__ W_attn, const float* __restrict__ b_attn,
    const float* __restrict__ ws_ht,
    const unsigned short* __restrict__ encb, const unsigned short* __restrict__ wab,
    const float* __restrict__ v, float* __restrict__ spart)
{
    __shared__ unsigned short As[2][64 * 64];
    __shared__ unsigned short Bs[2][64 * 64];
    __shared__ float qsh[64], vsh[64];
    int bx = blockIdx.x, by = blockIdx.y;
    int s0 = bx * 64, h0 = by * 64;
    int tid = threadIdx.x;
    int wave = tid >> 6, lane = tid & 63;

    // staging addresses (chunk-XOR swizzle; linear LDS dest)
    int r0 = tid >> 3, p0 = tid & 7;
    int lc = (p0 ^ (r0 & 7)) * 8;
    const unsigned short* aS0 = encb + (size_t)(s0 + r0) * E_ + lc;
    const unsigned short* aS1 = encb + (size_t)(s0 + 32 + r0) * E_ + lc;
    const unsigned short* bS0 = wab  + (size_t)(h0 + r0) * E_ + lc;
    const unsigned short* bS1 = wab  + (size_t)(h0 + 32 + r0) * E_ + lc;

    // stage tile 0 — latency hides under the q-prologue
    gload16(aS0, As[0] + tid * 8);
    gload16(aS1, As[0] + (tid + 256) * 8);
    gload16(bS0, Bs[0] + tid * 8);
    gload16(bS1, Bs[0] + (tid + 256) * 8);

    // ---- q prologue: 4 batches x 4 rows per wave ----
    {
        float4 hv[4];
        #pragma unroll
        for (int it = 0; it < 4; ++it)
            hv[it] = *(const float4*)(ws_ht + (lane + it * 64) * 4);
        #pragma unroll 1
        for (int bq = 0; bq < 4; ++bq) {
            int rbase = h0 + wave * 16 + bq * 4;
            float qa[4];
            #pragma unroll
            for (int rr = 0; rr < 4; ++rr) {
                const float* rowp = W_attn + (size_t)(rbase + rr) * (E_ + H_);
                float a = 0.f;
                #pragma unroll
                for (int it = 0; it < 4; ++it) {
                    float4 wv = *(const float4*)(rowp + (lane + it * 64) * 4);
                    a = fmaf(wv.x, hv[it].x, a); a = fmaf(wv.y, hv[it].y, a);
                    a = fmaf(wv.z, hv[it].z, a); a = fmaf(wv.w, hv[it].w, a);
                }
                qa[rr] = a;
            }
            #pragma unroll
            for (int rr = 0; rr < 4; ++rr) {
                #pragma unroll
                for (int m = 32; m; m >>= 1) qa[rr] += __shfl_down(qa[rr], m, 64);
            }
            if (lane == 0) {
                #pragma unroll
                for (int rr = 0; rr < 4; ++rr)
                    qsh[wave * 16 + bq * 4 + rr] = qa[rr] + b_attn[rbase + rr];
            }
        }
    }
    if (tid < 64) vsh[tid] = v[h0 + tid];

    int wr = (wave >> 1) * 32, wc = (wave & 1) * 32;
    int fc = lane & 15, g = lane >> 4;
    int aRow[2], bRow[2], pc[2];
    #pragma unroll
    for (int m = 0; m < 2; ++m) aRow[m] = (wr + m * 16 + fc) * 64;
    #pragma unroll
    for (int n = 0; n < 2; ++n) bRow[n] = (wc + n * 16 + fc) * 64;
    #pragma unroll
    for (int kk = 0; kk < 2; ++kk) pc[kk] = ((kk * 4 + g) ^ (fc & 7)) * 8;

    f32x4 acc[2][2];
    #pragma unroll
    for (int m = 0; m < 2; ++m)
        #pragma unroll
        for (int n = 0; n < 2; ++n)
            acc[m][n] = (f32x4){0.f, 0.f, 0.f, 0.f};

    __syncthreads();   // tile 0 staged (vmcnt drained)
    int cur = 0;
    #pragma unroll 1
    for (int t = 0; t < 16; ++t) {
        if (t < 15) {   // issue next-tile stage BEFORE compute (T3 2-phase)
            int k0 = (t + 1) * 64;
            gload16(aS0 + k0, As[cur ^ 1] + tid * 8);
            gload16(aS1 + k0, As[cur ^ 1] + (tid + 256) * 8);
            gload16(bS0 + k0, Bs[cur ^ 1] + tid * 8);
            gload16(bS1 + k0, Bs[cur ^ 1] + (tid + 256) * 8);
        }
        #pragma unroll
        for (int kk = 0; kk < 2; ++kk) {
            bf16x8 af[2], bf2[2];
            #pragma unroll
            for (int m = 0; m < 2; ++m) af[m] = *(const bf16x8*)(As[cur] + aRow[m] + pc[kk]);
            #pragma unroll
            for (int n = 0; n < 2; ++n) bf2[n] = *(const bf16x8*)(Bs[cur] + bRow[n] + pc[kk]);
            #pragma unroll
            for (int m = 0; m < 2; ++m)
                #pragma unroll
                for (int n = 0; n < 2; ++n)
                    acc[m][n] = __builtin_amdgcn_mfma_f32_16x16x32_bf16(
                        af[m], bf2[n], acc[m][n], 0, 0, 0);
        }
        __syncthreads();   // next tile staged + this buf's LDS reads done
        cur ^= 1;
    }

    // ---- epilogue: partial scores ----
    float qv[2], vv[2];
    #pragma unroll
    for (int n = 0; n < 2; ++n) {
        int col = wc + n * 16 + fc;
        qv[n] = qsh[col];
        vv[n] = vsh[col];
    }
    int part = by * 2 + (wave & 1);
    #pragma unroll
    for (int m = 0; m < 2; ++m) {
        #pragma unroll
        for (int j = 0; j < 4; ++j) {
            float p = 0.f;
            #pragma unroll
            for (int n = 0; n < 2; ++n)
                p += tanhf(acc[m][n][j] + qv[n]) * vv[n];
            #pragma unroll
            for (int mask = 8; mask; mask >>= 1) p += __shfl_xor(p, mask, 64);
            if (fc == 0)
                spart[(size_t)(s0 + wr + m * 16 + g * 4 + j) * 32 + part] = p;
        }
    }
}

// ---------------- KD: e = exp(sum spart); gpart; ctxU (4 copies) += e * enc ----------------
__global__ __launch_bounds__(256) void kD(
    const float* __restrict__ spart, const unsigned short* __restrict__ encb,
    float* __restrict__ expw, float* __restrict__ gpart, float* __restrict__ ctx)
{
    __shared__ float esh[16];
    int b = blockIdx.x, tid = threadIdx.x;
    int s0 = b * 16;
    int sl = tid >> 4, pp = tid & 15;
    float vsum = spart[(size_t)(s0 + sl) * 32 + pp]
               + spart[(size_t)(s0 + sl) * 32 + pp + 16];
    #pragma unroll
    for (int mask = 8; mask; mask >>= 1) vsum += __shfl_xor(vsum, mask, 64);
    if (pp == 0) {
        float e = expf(vsum);
        expw[s0 + sl] = e;
        esh[sl] = e;
    }
    __syncthreads();
    if (tid == 0) {
        float bs = 0.f;
        #pragma unroll
        for (int i = 0; i < 16; ++i) bs += esh[i];
        gpart[b] = bs;
    }
    int e0 = tid * 4;
    float a0 = 0.f, a1 = 0.f, a2 = 0.f, a3 = 0.f;
    #pragma unroll
    for (int ss = 0; ss < 16; ++ss) {
        ushort4 u = *(const ushort4*)(encb + (size_t)(s0 + ss) * E_ + e0);
        float w = esh[ss];
        a0 = fmaf(w, bf2f(u.x), a0);
        a1 = fmaf(w, bf2f(u.y), a1);
        a2 = fmaf(w, bf2f(u.z), a2);
        a3 = fmaf(w, bf2f(u.w), a3);
    }
    float* cdst = ctx + (b & 3) * 1024;   // 4-way copies: 32 contenders/address
    atomicAdd(&cdst[e0 + 0], a0);
    atomicAdd(&cdst[e0 + 1], a1);
    atomicAdd(&cdst[e0 + 2], a2);
    atomicAdd(&cdst[e0 + 3], a3);
}

// ---------------- KE: ht_tilda (blocks 0..255, wave-per-row) ; out_w (256..257) ----------------
__global__ __launch_bounds__(256) void kE(
    const float* __restrict__ W_ah, const float* __restrict__ b_ah,
    const float* __restrict__ ctx, const float* __restrict__ ht,
    const float* __restrict__ gpart, const float* __restrict__ expw,
    float* __restrict__ out_htt, float* __restrict__ ws_htt,
    float* __restrict__ out_w)
{
    int b = blockIdx.x;
    int wave = threadIdx.x >> 6, lane = threadIdx.x & 63;
    float gsum = gpart[lane] + gpart[lane + 64];
    #pragma unroll
    for (int m = 32; m; m >>= 1) gsum += __shfl_xor(gsum, m, 64);
    float invS = 1.0f / gsum;
    if (b >= 256) {
        int s = (b - 256) * 1024 + (int)threadIdx.x * 4;
        float4 e4 = *(const float4*)(expw + s);
        float4 w4 = { e4.x * invS, e4.y * invS, e4.z * invS, e4.w * invS };
        *(float4*)(out_w + s) = w4;
        return;
    }
    int r = b * 4 + wave;
    const float* row = W_ah + (size_t)r * (E_ + H_);
    float acc = 0.f;
    #pragma unroll
    for (int it = 0; it < 8; ++it) {
        int idx = (lane + it * 64) * 4;
        float4 wv = *(const float4*)(row + idx);
        float4 xv;
        if (idx < E_) {
            float4 c0v = *(const float4*)(ctx + idx);
            float4 c1v = *(const float4*)(ctx + 1024 + idx);
            float4 c2v = *(const float4*)(ctx + 2048 + idx);
            float4 c3v = *(const float4*)(ctx + 3072 + idx);
            xv = (float4){ (c0v.x + c1v.x + c2v.x + c3v.x) * invS,
                           (c0v.y + c1v.y + c2v.y + c3v.y) * invS,
                           (c0v.z + c1v.z + c2v.z + c3v.z) * invS,
                           (c0v.w + c1v.w + c2v.w + c3v.w) * invS };
        } else {
            xv = *(const float4*)(ht + idx - E_);
        }
        acc = fmaf(wv.x, xv.x, acc); acc = fmaf(wv.y, xv.y, acc);
        acc = fmaf(wv.z, xv.z, acc); acc = fmaf(wv.w, xv.w, acc);
    }
    #pragma unroll
    for (int m = 32; m; m >>= 1) acc += __shfl_down(acc, m, 64);
    if (lane == 0) {
        float val = tanhf(acc + b_ah[r]);
        out_htt[r] = val;
        ws_htt[r]  = val;
    }
}

// ---------------- KF: logits (4 rows/wave) + per-block expsum ----------------
// 2000 blocks x 256 thr; 16 rows/block.
__global__ __launch_bounds__(256) void kF(
    const float* __restrict__ W_out, const float* __restrict__ b_out,
    const float* __restrict__ ht_tilda, float* __restrict__ logits,
    float* __restrict__ lpart)
{
    __shared__ float wes[4];
    int b = blockIdx.x;
    int wave = threadIdx.x >> 6, lane = threadIdx.x & 63;
    int r0 = b * 16 + wave * 4;
    const float* w0 = W_out + (size_t)r0 * H_;
    const float* w1 = W_out + (size_t)(r0 + 1) * H_;
    const float* w2 = W_out + (size_t)(r0 + 2) * H_;
    const float* w3 = W_out + (size_t)(r0 + 3) * H_;
    float a0 = 0.f, a1 = 0.f, a2 = 0.f, a3 = 0.f;
    #pragma unroll
    for (int it = 0; it < 4; ++it) {
        int idx = (lane + it * 64) * 4;
        float4 hv = *(const float4*)(ht_tilda + idx);
        float4 v0 = *(const float4*)(w0 + idx);
        float4 v1 = *(const float4*)(w1 + idx);
        float4 v2 = *(const float4*)(w2 + idx);
        float4 v3 = *(const float4*)(w3 + idx);
        a0 = fmaf(v0.x, hv.x, a0); a0 = fmaf(v0.y, hv.y, a0);
        a0 = fmaf(v0.z, hv.z, a0); a0 = fmaf(v0.w, hv.w, a0);
        a1 = fmaf(v1.x, hv.x, a1); a1 = fmaf(v1.y, hv.y, a1);
        a1 = fmaf(v1.z, hv.z, a1); a1 = fmaf(v1.w, hv.w, a1);
        a2 = fmaf(v2.x, hv.x, a2); a2 = fmaf(v2.y, hv.y, a2);
        a2 = fmaf(v2.z, hv.z, a2); a2 = fmaf(v2.w, hv.w, a2);
        a3 = fmaf(v3.x, hv.x, a3); a3 = fmaf(v3.y, hv.y, a3);
        a3 = fmaf(v3.z, hv.z, a3); a3 = fmaf(v3.w, hv.w, a3);
    }
    #pragma unroll
    for (int m = 32; m; m >>= 1) {
        a0 += __shfl_down(a0, m, 64); a1 += __shfl_down(a1, m, 64);
        a2 += __shfl_down(a2, m, 64); a3 += __shfl_down(a3, m, 64);
    }
    if (lane == 0) {
        float lg0 = a0 + b_out[r0];
        float lg1 = a1 + b_out[r0 + 1];
        float lg2 = a2 + b_out[r0 + 2];
        float lg3 = a3 + b_out[r0 + 3];
        logits[r0]     = lg0;
        logits[r0 + 1] = lg1;
        logits[r0 + 2] = lg2;
        logits[r0 + 3] = lg3;
        wes[wave] = expf(lg0) + expf(lg1) + expf(lg2) + expf(lg3);
    }
    __syncthreads();
    if (threadIdx.x == 0)
        lpart[b] = wes[0] + wes[1] + wes[2] + wes[3];
}

// ---------------- KG: lse (redundant x8) + subtract ----------------
__global__ __launch_bounds__(1024) void kG(
    float* __restrict__ out, const float* __restrict__ lpart)
{
    __shared__ float sred[16];
    int b = blockIdx.x, tid = threadIdx.x;
    float s = 0.f;
    #pragma unroll
    for (int k = 0; k < 2; ++k) {
        int i = tid + k * 1024;
        if (i < 2000) s += lpart[i];
    }
    #pragma unroll
    for (int m = 32; m; m >>= 1) s += __shfl_down(s, m, 64);
    if ((tid & 63) == 0) sred[tid >> 6] = s;
    __syncthreads();
    float tot = 0.f;
    #pragma unroll
    for (int i = 0; i < 16; ++i) tot += sred[i];
    float lse = logf(tot);
    #pragma unroll
    for (int k = 0; k < 4; ++k) {
        int row = b * 4000 + k * 1024 + tid;
        if (row < (b + 1) * 4000 && row < V_) out[row] -= lse;
    }
}

extern "C" void kernel_launch(void* const* d_in, const int* in_sizes, int n_in,
                              void* d_out, int out_size, void* d_ws, size_t ws_size,
                              hipStream_t stream) {
    const float* enc          = (const float*)d_in[0];
    const int*   word         = (const int*)  d_in[1];
    const float* last_context = (const float*)d_in[2];
    const float* h0           = (const float*)d_in[3];
    const float* c0           = (const float*)d_in[4];
    const float* emb          = (const float*)d_in[5];
    const float* W_ih         = (const float*)d_in[6];
    const float* W_hh         = (const float*)d_in[7];
    const float* b_ih         = (const float*)d_in[8];
    const float* b_hh         = (const float*)d_in[9];
    const float* W_attn       = (const float*)d_in[10];
    const float* b_attn       = (const float*)d_in[11];
    const float* v            = (const float*)d_in[12];
    const float* W_ah         = (const float*)d_in[13];
    const float* b_ah         = (const float*)d_in[14];
    const float* W_out        = (const float*)d_in[15];
    const float* b_out        = (const float*)d_in[16];

    float* out        = (float*)d_out;
    float* out_logits = out;                 // 32000
    float* out_ht     = out + V_;            // 1024
    float* out_c      = out + V_ + H_;       // 1024
    float* out_htt    = out + V_ + 2 * H_;   // 1024
    float* out_w      = out + V_ + 3 * H_;   // 2048

    float* ws      = (float*)d_ws;
    float* ws_ht   = ws;             // 1024
    float* ws_expw = ws + 1024;      // 2048
    float* ws_ctx  = ws + 3072;      // 4096 (4 copies x 1024)
    float* ws_gp   = ws + 7168;      // 128
    float* ws_htt  = ws + 7296;      // 1024
    float* ws_lp   = ws + 8320;      // 2000
    float* ws_sp   = ws + 16384;     // 2048*32
    unsigned short* encb = (unsigned short*)(ws + 81920);  // 2048*1024 bf16
    unsigned short* wab  = encb + (size_t)S_ * E_;         // 1024*1024 bf16

    kA<<<1536, 256, 0, stream>>>(W_ih, W_hh, b_ih, b_hh, last_context, emb, word,
                                 h0, c0, enc, W_attn, out_ht, out_c, ws_ht,
                                 encb, wab, ws_ctx);
    kC<<<dim3(32, 16), 256, 0, stream>>>(W_attn, b_attn, ws_ht, encb, wab, v, ws_sp);
    kD<<<128, 256, 0, stream>>>(ws_sp, encb, ws_expw, ws_gp, ws_ctx);
    kE<<<258, 256, 0, stream>>>(W_ah, b_ah, ws_ctx, ws_ht, ws_gp, ws_expw,
                                out_htt, ws_htt, out_w);
    kF<<<2000, 256, 0, stream>>>(W_out, b_out, ws_htt, out_logits, ws_lp);
    kG<<<8, 1024, 0, stream>>>(out_logits, ws_lp);
}